// Round 5
// baseline (924.504 us; speedup 1.0000x reference)
//
#include <hip/hip_runtime.h>

typedef __attribute__((ext_vector_type(8))) short bf16x8;
typedef __attribute__((ext_vector_type(4))) float f32x4;

#define DEVINL __device__ __forceinline__
#define AS1 __attribute__((address_space(1)))
#define AS3 __attribute__((address_space(3)))

constexpr int BB = 4, SS = 4096, DD = 1024, LL = 8192;
constexpr int LTILE = 128, STILE = 128, BK = 64;
constexpr int NST = SS / STILE;              // 32 s-tiles (whole sequence)
constexpr int KST = DD / BK;                 // 16 k-steps per phase
constexpr int NU  = NST * 2 * KST;           // 1024 pipeline units
constexpr int A_SH = LTILE * BK;             // 8192 shorts (16 KiB)
constexpr int B_SH = STILE * BK;             // 8192 shorts (16 KiB)
constexpr int SLOT_SH = A_SH + B_SH;         // 16384 shorts (32 KiB)
constexpr int NSLOT = 4;                     // 128 KiB total -> 1 block/CU

DEVINL unsigned short f2bf(float f){
  union { float f; unsigned u; } a; a.f = f;
  unsigned r = a.u + 0x7fffu + ((a.u >> 16) & 1u);   // RNE
  return (unsigned short)(r >> 16);
}

DEVINL void gll16(const void* src, void* dst){
  __builtin_amdgcn_global_load_lds((const AS1 unsigned int*)src,
                                   (AS3 unsigned int*)dst, 16, 0, 0);
}

// read one MFMA operand fragment: 8 contiguous bf16 at (row, 8-elem chunk),
// xor-8 swizzle matching the pre-swizzled global source in staging.
DEVINL bf16x8 read_frag(const unsigned short* tile, int row, int chunk){
  return *(const AS3 bf16x8*)(tile + row*BK + ((chunk ^ (row & 7)) << 3));
}

__global__ void conv_kernel(const float4* __restrict__ in,
                            ushort4* __restrict__ out, int n4){
  int stride = gridDim.x * blockDim.x;
  for (int i = blockIdx.x*blockDim.x + threadIdx.x; i < n4; i += stride){
    float4 v = in[i];
    ushort4 o;
    o.x = f2bf(v.x); o.y = f2bf(v.y); o.z = f2bf(v.z); o.w = f2bf(v.w);
    out[i] = o;
  }
}

// ---------------- zgemm (round-1 structure, 128x128 tile, 256 thr) --------
constexpr int ZTILE = 128 * BK;   // 8192 shorts per staged tile

DEVINL void stage_tile128(const unsigned short* __restrict__ g0, int row0, int d0,
                          unsigned short* ldsbase, int wave, int lane){
#pragma unroll
  for (int it = 0; it < 4; ++it){
    int off  = it*4096 + wave*1024 + lane*16;   // byte offset inside tile
    int row  = off >> 7;                        // 128 B per row
    int slot = (off >> 4) & 7;
    int scol = (slot ^ (row & 7)) << 3;
    gll16(g0 + (size_t)(row0 + row) * DD + d0 + scol,
          ldsbase + ((it*4096 + wave*1024) >> 1));
  }
}

__global__ __launch_bounds__(256, 2) void zgemm_kernel(
    const unsigned short* __restrict__ X, const unsigned short* __restrict__ W,
    const float* __restrict__ Wb, unsigned short* __restrict__ Z)
{
  __shared__ __align__(16) unsigned short lds[2*ZTILE];   // 32 KiB
  const int bid = blockIdx.x;
  const int tm = bid & 127;
  const int tn = bid >> 7;
  const int tid = threadIdx.x, wave = tid >> 6, lane = tid & 63;
  const int wl = wave >> 1, wn = wave & 1;
  const int g = lane >> 4, cc = lane & 15;

  f32x4 acc[4][4] = {};
#pragma unroll 1
  for (int ks = 0; ks < KST; ++ks){
    __syncthreads();
    stage_tile128(X, tm*128, ks*BK, lds,         wave, lane);
    stage_tile128(W, tn*128, ks*BK, lds + ZTILE, wave, lane);
    __syncthreads();
#pragma unroll
    for (int ksub = 0; ksub < 2; ++ksub){
      bf16x8 af[4], bfr[4];
#pragma unroll
      for (int f = 0; f < 4; ++f) af[f]  = read_frag(lds,         wl*64 + f*16 + cc, ksub*4 + g);
#pragma unroll
      for (int f = 0; f < 4; ++f) bfr[f] = read_frag(lds + ZTILE, wn*64 + f*16 + cc, ksub*4 + g);
#pragma unroll
      for (int fm = 0; fm < 4; ++fm)
#pragma unroll
        for (int fn = 0; fn < 4; ++fn)
          acc[fm][fn] = __builtin_amdgcn_mfma_f32_16x16x32_bf16(af[fm], bfr[fn], acc[fm][fn], 0, 0, 0);
    }
  }
#pragma unroll
  for (int fm = 0; fm < 4; ++fm)
#pragma unroll
    for (int fn = 0; fn < 4; ++fn)
#pragma unroll
      for (int r = 0; r < 4; ++r){
        int row = tm*128 + wl*64 + fm*16 + 4*g + r;
        int col = tn*128 + wn*64 + fn*16 + cc;
        float y = acc[fm][fn][r] + Wb[col];
        float e2 = __expf(2.f * y);
        float t = 1.f - 2.f / (e2 + 1.f);
        Z[(size_t)row*DD + col] = f2bf(t);
      }
}

// ---------------- fused: pipelined dual-GEMM + exp-weighted reduce --------
// 256 blocks x 256 thr (4 waves) = 1 block/CU, 1 wave/SIMD, full 512-reg
// budget (no spill). Per block: (lt, b) -> 128 L x 4096 S. Flat pipeline of
// NU=1024 units; unit u = (s-tile u>>5, phase (u>>4)&1, k u&15). Phase 0
// stages (F, X[st]) -> gacc; phase 1 stages (U, Z[st]) -> sacc. 4 LDS slots,
// prefetch depth 3, steady s_waitcnt vmcnt(16), ONE barrier per unit: at the
// top-of-u barrier all waves have consumed slot (u-1)&3 (their unit-(u-1)
// lgkm-waited ds_reads precede the barrier in program order), and stage(u+3)
// targets exactly that slot.
__global__ __launch_bounds__(256, 1) void fused_kernel(
    const unsigned short* __restrict__ U, const unsigned short* __restrict__ F,
    const unsigned short* __restrict__ Z, const unsigned short* __restrict__ X,
    float* __restrict__ pse, float* __restrict__ pac)
{
  __shared__ __align__(16) unsigned short lds[NSLOT * SLOT_SH];   // 128 KiB

  const int h = blockIdx.x;            // 256 blocks, 1 per CU
  // XCD x owns lt in [x*8, x*8+8) (U/F A-set = 4 MB ~ its L2) and all 4 b.
  const int xcd = h & 7, j = h >> 3;   // j in 0..31
  const int lt = xcd * 8 + (j & 7);    // 0..63
  const int b  = j >> 3;               // 0..3

  const int tid = threadIdx.x;
  const int wave = tid >> 6, lane = tid & 63;
  const int wl = wave >> 1, ws = wave & 1;     // 2 L-waves x 2 S-waves
  const int g = lane >> 4, cc = lane & 15;

  const unsigned short* Ub = U + (size_t)lt * LTILE * DD;
  const unsigned short* Fb = F + (size_t)lt * LTILE * DD;
  const unsigned short* Zb = Z + (size_t)b * SS * DD;
  const unsigned short* Xb = X + (size_t)b * SS * DD;

  // staging offsets: [128 x 64]-short tile = 1024 16B-chunks; thread handles
  // chunks {tid, tid+256, tid+512, tid+768}. Pre-swizzled global source,
  // linear LDS dest (A and B tiles both have row stride DD in global).
  int aoff[4];
#pragma unroll
  for (int it = 0; it < 4; ++it){
    int c = it*256 + tid, row = c >> 3, s0 = c & 7;
    aoff[it] = row*DD + ((s0 ^ (row & 7)) << 3);
  }

  f32x4 sacc[4][4] = {}, gacc[4][4] = {};
  float se_st[4][4] = {}, ac_st[4][4] = {};

  // ---- stage unit u into slot (8 gll16 per thread) ----
  auto stage_unit = [&](int u, int slot){
    const int st = u >> 5, ph = (u >> 4) & 1, k64 = (u & 15) * 64;
    const unsigned short* As = ph ? Ub : Fb;
    const unsigned short* Bs = (ph ? Zb : Xb) + (size_t)st * (STILE * DD);
    unsigned short* sl = lds + slot * SLOT_SH;
#pragma unroll
    for (int it = 0; it < 4; ++it)
      gll16(As + aoff[it] + k64, sl + (it*256 + tid)*8);
#pragma unroll
    for (int it = 0; it < 4; ++it)
      gll16(Bs + aoff[it] + k64, sl + A_SH + (it*256 + tid)*8);
  };

  stage_unit(0, 0);
  stage_unit(1, 1);
  stage_unit(2, 2);

#pragma unroll 1
  for (int u = 0; u < NU; ++u){
    // own unit-u loads complete (16 of units u+1,u+2 stay in flight).
    asm volatile("s_waitcnt vmcnt(16)" ::: "memory");
    __builtin_amdgcn_s_barrier();

    // prefetch unit u+3 into slot (u+3)&3 == (u-1)&3, whose readers all
    // finished before the barrier above. Tail wrap keeps vmcnt uniform
    // (wrapped stages are harmless re-loads nobody reads).
    int un = u + 3; if (un >= NU) un -= NU;      // NU%4==0 -> un&3==(u+3)&3
    stage_unit(un, un & 3);

    const unsigned short* At = lds + (u & 3) * SLOT_SH;   // [128][64]
    const unsigned short* Bt = At + A_SH;                 // [128][64]
    const int ph = (u >> 4) & 1;

#pragma unroll
    for (int ksub = 0; ksub < 2; ++ksub){
      bf16x8 a0[4], b0[4];
#pragma unroll
      for (int f = 0; f < 4; ++f) a0[f] = read_frag(At, wl*64 + f*16 + cc, ksub*4 + g);
#pragma unroll
      for (int f = 0; f < 4; ++f) b0[f] = read_frag(Bt, ws*64 + f*16 + cc, ksub*4 + g);
      if (ph == 0){
#pragma unroll
        for (int fm = 0; fm < 4; ++fm)
#pragma unroll
          for (int fn = 0; fn < 4; ++fn)
            gacc[fm][fn] = __builtin_amdgcn_mfma_f32_16x16x32_bf16(a0[fm], b0[fn], gacc[fm][fn], 0, 0, 0);
      } else {
#pragma unroll
        for (int fm = 0; fm < 4; ++fm)
#pragma unroll
          for (int fn = 0; fn < 4; ++fn)
            sacc[fm][fn] = __builtin_amdgcn_mfma_f32_16x16x32_bf16(a0[fm], b0[fn], sacc[fm][fn], 0, 0, 0);
      }
    }

    // end of s-tile (after ph=1 k=15): exp-weight scores, fold G, reset.
    if ((u & 31) == 31){
#pragma unroll
      for (int fm = 0; fm < 4; ++fm)
#pragma unroll
        for (int r = 0; r < 4; ++r){
          float ps = 0.f, pg = 0.f;
#pragma unroll
          for (int fn = 0; fn < 4; ++fn){
            float p = __expf(sacc[fm][fn][r]);     // |score| << 88, max-free safe
            ps += p;
            pg += p * gacc[fm][fn][r];
          }
          se_st[fm][r] += ps;
          ac_st[fm][r] += pg;
        }
#pragma unroll
      for (int fm = 0; fm < 4; ++fm)
#pragma unroll
        for (int fn = 0; fn < 4; ++fn){
          sacc[fm][fn] = f32x4{0.f, 0.f, 0.f, 0.f};
          gacc[fm][fn] = f32x4{0.f, 0.f, 0.f, 0.f};
        }
    }
  }

  // reduce across the 16 s-columns per lane group, write per-ws partials
#pragma unroll
  for (int fm = 0; fm < 4; ++fm)
#pragma unroll
    for (int r = 0; r < 4; ++r){
      float s = se_st[fm][r], a = ac_st[fm][r];
#pragma unroll
      for (int m = 1; m < 16; m <<= 1){
        s += __shfl_xor(s, m, 64);
        a += __shfl_xor(a, m, 64);
      }
      if (cc == 0){
        int l = lt*LTILE + wl*64 + fm*16 + 4*g + r;
        size_t idx = (((size_t)b*LL + l) << 1) + ws;   // [B][L][2 wave-halves]
        pse[idx] = s;
        pac[idx] = a;
      }
    }
}

__global__ void combine_kernel(const float* __restrict__ pse, const float* __restrict__ pac,
                               const float* __restrict__ fb, float* __restrict__ out)
{
  int i = blockIdx.x*blockDim.x + threadIdx.x;
  if (i >= BB*LL) return;
  int l = i & (LL - 1);
  float s = pse[(size_t)i*2] + pse[(size_t)i*2 + 1];
  float a = pac[(size_t)i*2] + pac[(size_t)i*2 + 1];
  out[i] = a / s + fb[l];
}

extern "C" void kernel_launch(void* const* d_in, const int* in_sizes, int n_in,
                              void* d_out, int out_size, void* d_ws, size_t ws_size,
                              hipStream_t stream)
{
  const float* inp = (const float*)d_in[0];   // [B,S,D]
  const float* Ww  = (const float*)d_in[1];   // [D,D]
  const float* Wb  = (const float*)d_in[2];   // [D]
  const float* Uw  = (const float*)d_in[3];   // [L,D]
  const float* Fw  = (const float*)d_in[4];   // [L,D]
  const float* fb  = (const float*)d_in[5];   // [L]
  float* out = (float*)d_out;

  char* ws = (char*)d_ws;
  unsigned short* Xbf = (unsigned short*)(ws);                            // 32 MiB
  unsigned short* Zbf = (unsigned short*)(ws + (size_t)32*1024*1024);     // 32 MiB
  unsigned short* Ubf = (unsigned short*)(ws + (size_t)64*1024*1024);     // 16 MiB
  unsigned short* Fbf = (unsigned short*)(ws + (size_t)80*1024*1024);     // 16 MiB
  unsigned short* Wbf = (unsigned short*)(ws + (size_t)96*1024*1024);     //  2 MiB
  float* pse = (float*)(ws + (size_t)98*1024*1024);                       // 256 KiB
  float* pac = (float*)(ws + (size_t)99*1024*1024);                       // 256 KiB

  conv_kernel<<<2048, 256, 0, stream>>>((const float4*)inp, (ushort4*)Xbf, BB*SS*DD/4);
  conv_kernel<<<256,  256, 0, stream>>>((const float4*)Ww,  (ushort4*)Wbf, DD*DD/4);
  conv_kernel<<<1024, 256, 0, stream>>>((const float4*)Uw,  (ushort4*)Ubf, LL*DD/4);
  conv_kernel<<<1024, 256, 0, stream>>>((const float4*)Fw,  (ushort4*)Fbf, LL*DD/4);

  zgemm_kernel<<<128*8, 256, 0, stream>>>(Xbf, Wbf, Wb, Zbf);
  fused_kernel<<<256, 256, 0, stream>>>(Ubf, Fbf, Zbf, Xbf, pse, pac);
  combine_kernel<<<(BB*LL + 255)/256, 256, 0, stream>>>(pse, pac, fb, out);
}

// Round 6
// 656.298 us; speedup vs baseline: 1.4087x; 1.4087x over previous
//
#include <hip/hip_runtime.h>

typedef __attribute__((ext_vector_type(8))) short bf16x8;
typedef __attribute__((ext_vector_type(4))) float f32x4;
typedef unsigned short us;

#define DEVINL __device__ __forceinline__
#define AS1 __attribute__((address_space(1)))
#define AS3 __attribute__((address_space(3)))

constexpr int BB = 4, SS = 4096, DD = 1024, LL = 8192;
// fused-kernel geometry
constexpr int LT_ = 128;            // L rows per block
constexpr int STB = 256;            // S rows per block-tile
constexpr int BK  = 32;             // K per unit
constexpr int NST = SS / STB;       // 16 s-tiles
constexpr int KST = DD / BK;        // 32 k-steps
constexpr int NU  = NST * KST;      // 512 units
constexpr int U_SH = LT_ * BK;      // 4096 shorts (8 KiB)
constexpr int Z_SH = STB * BK;      // 8192 shorts (16 KiB)
constexpr int SLOT_SH = 2*U_SH + 2*Z_SH;   // 24576 shorts (48 KiB)
// zgemm geometry
constexpr int ZKST = DD / 64;       // 16

DEVINL unsigned short f2bf(float f){
  union { float f; unsigned u; } a; a.f = f;
  unsigned r = a.u + 0x7fffu + ((a.u >> 16) & 1u);   // RNE
  return (unsigned short)(r >> 16);
}

DEVINL void gll16(const void* src, void* dst){
  __builtin_amdgcn_global_load_lds((const AS1 unsigned int*)src,
                                   (AS3 unsigned int*)dst, 16, 0, 0);
}

__global__ void conv_kernel(const float4* __restrict__ in,
                            ushort4* __restrict__ out, int n4){
  int stride = gridDim.x * blockDim.x;
  for (int i = blockIdx.x*blockDim.x + threadIdx.x; i < n4; i += stride){
    float4 v = in[i];
    ushort4 o;
    o.x = f2bf(v.x); o.y = f2bf(v.y); o.z = f2bf(v.z); o.w = f2bf(v.w);
    out[i] = o;
  }
}

// ---------------- zgemm (round-1 structure, proven) ----------------------
constexpr int ZTILE = 128 * 64;   // shorts per staged tile (BK=64 here)

DEVINL bf16x8 zread_frag(const us* tile, int row, int chunk){
  return *(const AS3 bf16x8*)(tile + row*64 + ((chunk ^ (row & 7)) << 3));
}

DEVINL void stage_tile128(const us* __restrict__ g0, int row0, int d0,
                          us* ldsbase, int wave, int lane){
#pragma unroll
  for (int it = 0; it < 4; ++it){
    int off  = it*4096 + wave*1024 + lane*16;   // byte offset inside tile
    int row  = off >> 7;                        // 128 B per row
    int slot = (off >> 4) & 7;
    int scol = (slot ^ (row & 7)) << 3;
    gll16(g0 + (size_t)(row0 + row) * DD + d0 + scol,
          ldsbase + ((it*4096 + wave*1024) >> 1));
  }
}

__global__ __launch_bounds__(256, 2) void zgemm_kernel(
    const us* __restrict__ X, const us* __restrict__ W,
    const float* __restrict__ Wb, us* __restrict__ Z)
{
  __shared__ __align__(16) us lds[2*ZTILE];   // 32 KiB
  const int bid = blockIdx.x;
  const int tm = bid & 127;
  const int tn = bid >> 7;
  const int tid = threadIdx.x, wave = tid >> 6, lane = tid & 63;
  const int wl = wave >> 1, wn = wave & 1;
  const int g = lane >> 4, cc = lane & 15;

  f32x4 acc[4][4] = {};
#pragma unroll 1
  for (int ks = 0; ks < ZKST; ++ks){
    __syncthreads();
    stage_tile128(X, tm*128, ks*64, lds,         wave, lane);
    stage_tile128(W, tn*128, ks*64, lds + ZTILE, wave, lane);
    __syncthreads();
#pragma unroll
    for (int ksub = 0; ksub < 2; ++ksub){
      bf16x8 af[4], bfr[4];
#pragma unroll
      for (int f = 0; f < 4; ++f) af[f]  = zread_frag(lds,         wl*64 + f*16 + cc, ksub*4 + g);
#pragma unroll
      for (int f = 0; f < 4; ++f) bfr[f] = zread_frag(lds + ZTILE, wn*64 + f*16 + cc, ksub*4 + g);
#pragma unroll
      for (int fm = 0; fm < 4; ++fm)
#pragma unroll
        for (int fn = 0; fn < 4; ++fn)
          acc[fm][fn] = __builtin_amdgcn_mfma_f32_16x16x32_bf16(af[fm], bfr[fn], acc[fm][fn], 0, 0, 0);
    }
  }
#pragma unroll
  for (int fm = 0; fm < 4; ++fm)
#pragma unroll
    for (int fn = 0; fn < 4; ++fn)
#pragma unroll
      for (int r = 0; r < 4; ++r){
        int row = tm*128 + wl*64 + fm*16 + 4*g + r;
        int col = tn*128 + wn*64 + fn*16 + cc;
        float y = acc[fm][fn][r] + Wb[col];
        float e2 = __expf(2.f * y);
        float t = 1.f - 2.f / (e2 + 1.f);
        Z[(size_t)row*DD + col] = f2bf(t);
      }
}

// ---------------- fused: fine-pipelined dual-GEMM + exp-weighted reduce ---
// 256 blocks x 512 thr (8 waves) = 1 block/CU = 2 waves/SIMD (TLP) with
// 144 KiB LDS. Per block: (lt, b) -> 128 L x 4096 S; per wave 64L x 64S
// dual accumulators (128 AGPR). Unit u = (s-tile u>>5, k-step u&31); each
// unit stages ALL FOUR k-slices (U,F,Z,X; 48 KiB) for unit u+2 and computes
// 16 score-MFMA + 16 G-MFMA. 3 LDS slots; ONE raw s_barrier per unit;
// steady s_waitcnt vmcnt(6) (stage(u+1)'s 6 loads always in flight, never
// drained). Stage(u+2) is issued AFTER the barrier: its target slot
// (u+2)%3 == (u-1)%3 was last read in unit u-1, and every wave completed
// those reads (lgkm-waited before its MFMAs) before passing this barrier.
// Bank math at BK=32 (64 B rows): ds_read_b128 bank base = 16*(row&1)+4g
// covers all 32 banks uniformly -> no swizzle needed (and gll16 dest stays
// linear per HW requirement).
__global__ __launch_bounds__(512, 2) void fused_kernel(
    const us* __restrict__ U, const us* __restrict__ F,
    const us* __restrict__ Z, const us* __restrict__ X,
    float* __restrict__ pse, float* __restrict__ pac)
{
  __shared__ __align__(16) us lds[3 * SLOT_SH];   // 144 KiB

  const int h = blockIdx.x;            // 256 blocks, 1 per CU
  // XCD x owns lt in [x*8, x*8+8): U/F set = 4 MB ~ its L2; the 8 lockstep
  // lt-blocks per (xcd,b) share the streaming Z/X window through L2/L3.
  const int xcd = h & 7, j = h >> 3;   // j in 0..31
  const int lt = xcd * 8 + (j & 7);    // 0..63
  const int b  = j >> 3;               // 0..3

  const int tid = threadIdx.x;
  const int wave = tid >> 6, lane = tid & 63;
  const int wl = wave >> 2, ws = wave & 3;     // 2 L-waves x 4 S-waves
  const int g = lane >> 4, cc = lane & 15;

  const us* Ub = U + (size_t)lt * LT_ * DD;
  const us* Fb = F + (size_t)lt * LT_ * DD;
  const us* Zb = Z + (size_t)b * SS * DD;
  const us* Xb = X + (size_t)b * SS * DD;

  // per-thread staging offset: chunk tid -> row tid>>2, 16B-slot tid&3
  // (rows are 64 B at BK=32). Same formula for all four tiles (stride DD).
  const int offA = (tid >> 2) * DD + (tid & 3) * 8;

  f32x4 sacc[4][4] = {}, gacc[4][4] = {};
  float se_pk = 0.f, ac_pk = 0.f;   // lane-packed running sums (pair = cc)

  // stage all 4 k-slices of unit n into slot n%3 (6 gll16 per thread)
  auto stage_unit = [&](int n){
    int nn = (n >= NU) ? n - NU : n;       // tail wrap: harmless re-loads
    us* sb = lds + (n % 3) * SLOT_SH;
    const int k32 = (nn & 31) * BK;
    const size_t stoff = (size_t)(nn >> 5) * STB * DD;
    gll16(Ub + k32 + offA, sb + tid*8);
    gll16(Fb + k32 + offA, sb + U_SH + tid*8);
    const us* pZ = Zb + stoff + k32 + offA;
    gll16(pZ,          sb + 2*U_SH + tid*8);
    gll16(pZ + 128*DD, sb + 2*U_SH + 4096 + tid*8);
    const us* pX = Xb + stoff + k32 + offA;
    gll16(pX,          sb + 2*U_SH + Z_SH + tid*8);
    gll16(pX + 128*DD, sb + 2*U_SH + Z_SH + 4096 + tid*8);
  };

  stage_unit(0);
  stage_unit(1);

#pragma unroll 1
  for (int u = 0; u < NU; ++u){
    // own unit-u loads landed; unit-(u+1)'s 6 stay in flight (never drain).
    asm volatile("s_waitcnt vmcnt(6)" ::: "memory");
    __builtin_amdgcn_s_barrier();
    // post-barrier issue: WAR-safe (slot (u+2)%3 readers all done above).
    stage_unit(u + 2);

    const us* sb = lds + (u % 3) * SLOT_SH;
    const us* tU = sb;
    const us* tF = sb + U_SH;
    const us* tZ = sb + 2*U_SH;
    const us* tX = sb + 2*U_SH + Z_SH;

    bf16x8 a0[4], b0[4], a1[4], b1[4];
#pragma unroll
    for (int f = 0; f < 4; ++f)
      a0[f] = *(const AS3 bf16x8*)(tU + (wl*64 + f*16 + cc)*BK + g*8);
#pragma unroll
    for (int f = 0; f < 4; ++f)
      b0[f] = *(const AS3 bf16x8*)(tZ + (ws*64 + f*16 + cc)*BK + g*8);
    __builtin_amdgcn_s_setprio(1);
#pragma unroll
    for (int fm = 0; fm < 4; ++fm)
#pragma unroll
      for (int fn = 0; fn < 4; ++fn)
        sacc[fm][fn] = __builtin_amdgcn_mfma_f32_16x16x32_bf16(a0[fm], b0[fn], sacc[fm][fn], 0, 0, 0);
    __builtin_amdgcn_s_setprio(0);

#pragma unroll
    for (int f = 0; f < 4; ++f)
      a1[f] = *(const AS3 bf16x8*)(tF + (wl*64 + f*16 + cc)*BK + g*8);
#pragma unroll
    for (int f = 0; f < 4; ++f)
      b1[f] = *(const AS3 bf16x8*)(tX + (ws*64 + f*16 + cc)*BK + g*8);
    __builtin_amdgcn_s_setprio(1);
#pragma unroll
    for (int fm = 0; fm < 4; ++fm)
#pragma unroll
      for (int fn = 0; fn < 4; ++fn)
        gacc[fm][fn] = __builtin_amdgcn_mfma_f32_16x16x32_bf16(a1[fm], b1[fn], gacc[fm][fn], 0, 0, 0);
    __builtin_amdgcn_s_setprio(0);

    // end of s-tile: exp-weight scores, fold G, butterfly-reduce over the
    // 16 s-columns (cc lanes), lane-pack into (se_pk, ac_pk), reset accs.
    if ((u & 31) == 31){
#pragma unroll
      for (int fm = 0; fm < 4; ++fm)
#pragma unroll
        for (int r = 0; r < 4; ++r){
          float ps = 0.f, pg = 0.f;
#pragma unroll
          for (int fn = 0; fn < 4; ++fn){
            float p = __expf(sacc[fm][fn][r]);   // |score| << 88, max-free safe
            ps += p;
            pg += p * gacc[fm][fn][r];
          }
#pragma unroll
          for (int m = 1; m < 16; m <<= 1){
            ps += __shfl_xor(ps, m, 64);
            pg += __shfl_xor(pg, m, 64);
          }
          bool sel = (cc == fm*4 + r);
          se_pk += sel ? ps : 0.f;
          ac_pk += sel ? pg : 0.f;
        }
#pragma unroll
      for (int fm = 0; fm < 4; ++fm)
#pragma unroll
        for (int fn = 0; fn < 4; ++fn){
          sacc[fm][fn] = f32x4{0.f, 0.f, 0.f, 0.f};
          gacc[fm][fn] = f32x4{0.f, 0.f, 0.f, 0.f};
        }
    }
  }

  // lane (g, cc) holds the (se, ac) sums for row (cc>>2)*16 + 4g + (cc&3)
  // of its wave's 64-row L-slice; each wave's ws is a separate partial.
  {
    int row = (cc >> 2)*16 + 4*g + (cc & 3);
    int l = lt*LT_ + wl*64 + row;
    size_t idx = ((size_t)b*LL + l)*4 + ws;
    pse[idx] = se_pk;
    pac[idx] = ac_pk;
  }
}

__global__ void combine_kernel(const float* __restrict__ pse, const float* __restrict__ pac,
                               const float* __restrict__ fb, float* __restrict__ out)
{
  int i = blockIdx.x*blockDim.x + threadIdx.x;
  if (i >= BB*LL) return;
  int l = i & (LL - 1);
  float s = 0.f, a = 0.f;
#pragma unroll
  for (int k = 0; k < 4; ++k){
    s += pse[(size_t)i*4 + k];
    a += pac[(size_t)i*4 + k];
  }
  out[i] = a / s + fb[l];
}

extern "C" void kernel_launch(void* const* d_in, const int* in_sizes, int n_in,
                              void* d_out, int out_size, void* d_ws, size_t ws_size,
                              hipStream_t stream)
{
  const float* inp = (const float*)d_in[0];   // [B,S,D]
  const float* Ww  = (const float*)d_in[1];   // [D,D]
  const float* Wb  = (const float*)d_in[2];   // [D]
  const float* Uw  = (const float*)d_in[3];   // [L,D]
  const float* Fw  = (const float*)d_in[4];   // [L,D]
  const float* fb  = (const float*)d_in[5];   // [L]
  float* out = (float*)d_out;

  char* ws = (char*)d_ws;
  us* Xbf = (us*)(ws);                            // 32 MiB
  us* Zbf = (us*)(ws + (size_t)32*1024*1024);     // 32 MiB
  us* Ubf = (us*)(ws + (size_t)64*1024*1024);     // 16 MiB
  us* Fbf = (us*)(ws + (size_t)80*1024*1024);     // 16 MiB
  us* Wbf = (us*)(ws + (size_t)96*1024*1024);     //  2 MiB
  float* pse = (float*)(ws + (size_t)98*1024*1024);   // 512 KiB
  float* pac = (float*)(ws + (size_t)99*1024*1024);   // 512 KiB

  conv_kernel<<<2048, 256, 0, stream>>>((const float4*)inp, (ushort4*)Xbf, BB*SS*DD/4);
  conv_kernel<<<256,  256, 0, stream>>>((const float4*)Ww,  (ushort4*)Wbf, DD*DD/4);
  conv_kernel<<<1024, 256, 0, stream>>>((const float4*)Uw,  (ushort4*)Ubf, LL*DD/4);
  conv_kernel<<<1024, 256, 0, stream>>>((const float4*)Fw,  (ushort4*)Fbf, LL*DD/4);

  zgemm_kernel<<<128*8, 256, 0, stream>>>(Xbf, Wbf, Wb, Zbf);
  fused_kernel<<<256, 512, 0, stream>>>(Ubf, Fbf, Zbf, Xbf, pse, pac);
  combine_kernel<<<(BB*LL + 255)/256, 256, 0, stream>>>(pse, pac, fb, out);
}

// Round 7
// 645.797 us; speedup vs baseline: 1.4316x; 1.0163x over previous
//
#include <hip/hip_runtime.h>

typedef __attribute__((ext_vector_type(8))) short bf16x8;
typedef __attribute__((ext_vector_type(4))) float f32x4;
typedef unsigned short us;

#define DEVINL __device__ __forceinline__
#define AS1 __attribute__((address_space(1)))
#define AS3 __attribute__((address_space(3)))

constexpr int BB = 4, SS = 4096, DD = 1024, LL = 8192;
// fused-kernel geometry
constexpr int LT_ = 128;            // L rows per block
constexpr int STB = 256;            // S rows per block-tile
constexpr int BK  = 32;             // K per unit
constexpr int NST = SS / STB;       // 16 s-tiles
constexpr int KST = DD / BK;        // 32 k-steps
constexpr int NU  = NST * KST;      // 512 units
constexpr int U_SH = LT_ * BK;      // 4096 shorts (8 KiB)
constexpr int Z_SH = STB * BK;      // 8192 shorts (16 KiB)
constexpr int SLOT_SH = 2*U_SH + 2*Z_SH;   // 24576 shorts (48 KiB)
// zgemm geometry
constexpr int ZKST = DD / 64;       // 16

DEVINL unsigned short f2bf(float f){
  union { float f; unsigned u; } a; a.f = f;
  unsigned r = a.u + 0x7fffu + ((a.u >> 16) & 1u);   // RNE
  return (unsigned short)(r >> 16);
}

DEVINL void gll16(const void* src, void* dst){
  __builtin_amdgcn_global_load_lds((const AS1 unsigned int*)src,
                                   (AS3 unsigned int*)dst, 16, 0, 0);
}

__global__ void conv_kernel(const float4* __restrict__ in,
                            ushort4* __restrict__ out, int n4){
  int stride = gridDim.x * blockDim.x;
  for (int i = blockIdx.x*blockDim.x + threadIdx.x; i < n4; i += stride){
    float4 v = in[i];
    ushort4 o;
    o.x = f2bf(v.x); o.y = f2bf(v.y); o.z = f2bf(v.z); o.w = f2bf(v.w);
    out[i] = o;
  }
}

// ---------------- zgemm (round-1 structure, proven, 0 conflicts) ---------
constexpr int ZTILE = 128 * 64;   // shorts per staged tile (BK=64 here)

DEVINL bf16x8 zread_frag(const us* tile, int row, int chunk){
  return *(const AS3 bf16x8*)(tile + row*64 + ((chunk ^ (row & 7)) << 3));
}

DEVINL void stage_tile128(const us* __restrict__ g0, int row0, int d0,
                          us* ldsbase, int wave, int lane){
#pragma unroll
  for (int it = 0; it < 4; ++it){
    int off  = it*4096 + wave*1024 + lane*16;   // byte offset inside tile
    int row  = off >> 7;                        // 128 B per row
    int slot = (off >> 4) & 7;
    int scol = (slot ^ (row & 7)) << 3;
    gll16(g0 + (size_t)(row0 + row) * DD + d0 + scol,
          ldsbase + ((it*4096 + wave*1024) >> 1));
  }
}

__global__ __launch_bounds__(256, 2) void zgemm_kernel(
    const us* __restrict__ X, const us* __restrict__ W,
    const float* __restrict__ Wb, us* __restrict__ Z)
{
  __shared__ __align__(16) us lds[2*ZTILE];   // 32 KiB
  const int bid = blockIdx.x;
  const int tm = bid & 127;
  const int tn = bid >> 7;
  const int tid = threadIdx.x, wave = tid >> 6, lane = tid & 63;
  const int wl = wave >> 1, wn = wave & 1;
  const int g = lane >> 4, cc = lane & 15;

  f32x4 acc[4][4] = {};
#pragma unroll 1
  for (int ks = 0; ks < ZKST; ++ks){
    __syncthreads();
    stage_tile128(X, tm*128, ks*64, lds,         wave, lane);
    stage_tile128(W, tn*128, ks*64, lds + ZTILE, wave, lane);
    __syncthreads();
#pragma unroll
    for (int ksub = 0; ksub < 2; ++ksub){
      bf16x8 af[4], bfr[4];
#pragma unroll
      for (int f = 0; f < 4; ++f) af[f]  = zread_frag(lds,         wl*64 + f*16 + cc, ksub*4 + g);
#pragma unroll
      for (int f = 0; f < 4; ++f) bfr[f] = zread_frag(lds + ZTILE, wn*64 + f*16 + cc, ksub*4 + g);
#pragma unroll
      for (int fm = 0; fm < 4; ++fm)
#pragma unroll
        for (int fn = 0; fn < 4; ++fn)
          acc[fm][fn] = __builtin_amdgcn_mfma_f32_16x16x32_bf16(af[fm], bfr[fn], acc[fm][fn], 0, 0, 0);
    }
  }
#pragma unroll
  for (int fm = 0; fm < 4; ++fm)
#pragma unroll
    for (int fn = 0; fn < 4; ++fn)
#pragma unroll
      for (int r = 0; r < 4; ++r){
        int row = tm*128 + wl*64 + fm*16 + 4*g + r;
        int col = tn*128 + wn*64 + fn*16 + cc;
        float y = acc[fm][fn][r] + Wb[col];
        float e2 = __expf(2.f * y);
        float t = 1.f - 2.f / (e2 + 1.f);
        Z[(size_t)row*DD + col] = f2bf(t);
      }
}

// ---------------- fused: fine-pipelined dual-GEMM + exp-weighted reduce ---
// Structure identical to round 6 EXCEPT the LDS slot swizzle.
//
// Bank-conflict fix (round-6 had 6.7e7 conflict-cycles): rows are 64 B =
// 4 slots of 16 B. Linear placement gives bank-group 16*(row&1)+4*g; a
// consecutive-8-lane read group (fixed g, rows r..r+7) covers only 2 of 8
// bank-groups -> 4-way conflict. Swizzle: logical chunk lg is stored at
// slot (lg + (row>>1)) & 3. Read slot for logical chunk g at row
// (..anything.. + cc): (g + (cc>>1)) & 3  (all other row terms are 0 mod 4).
// 8 consecutive lanes then cover all 8 (row&1, slot) combos -> 32 banks.
// Write side: gll16 LDS dest stays LINEAR (HW requirement); the swizzle is
// realized by pre-swizzling the per-lane GLOBAL source (rule 21):
// LDS chunk c (row=c>>2, slot=c&3) fetches logical chunk ((c&3)-(c>>3))&3.
__global__ __launch_bounds__(512, 2) void fused_kernel(
    const us* __restrict__ U, const us* __restrict__ F,
    const us* __restrict__ Z, const us* __restrict__ X,
    float* __restrict__ pse, float* __restrict__ pac)
{
  __shared__ __align__(16) us lds[3 * SLOT_SH];   // 144 KiB

  const int h = blockIdx.x;            // 256 blocks, 1 per CU
  const int xcd = h & 7, j = h >> 3;   // j in 0..31
  const int lt = xcd * 8 + (j & 7);    // 0..63
  const int b  = j >> 3;               // 0..3

  const int tid = threadIdx.x;
  const int wave = tid >> 6, lane = tid & 63;
  const int wl = wave >> 2, ws = wave & 3;     // 2 L-waves x 4 S-waves
  const int g = lane >> 4, cc = lane & 15;

  const us* Ub = U + (size_t)lt * LT_ * DD;
  const us* Fb = F + (size_t)lt * LT_ * DD;
  const us* Zb = Z + (size_t)b * SS * DD;
  const us* Xb = X + (size_t)b * SS * DD;

  // staging: LDS chunk c=tid -> row c>>2, slot c&3; fetch logical chunk
  // lg = ((c&3) - (c>>3)) & 3 of that row. (+512 chunks: row+=128, lg
  // unchanged since 64 = 0 mod 4 -> handled by +128*DD.)
  const int lg   = ((tid & 3) - (tid >> 3)) & 3;
  const int offA = (tid >> 2) * DD + lg * 8;

  // read-side swizzled slot (in shorts): all reads use row = X + cc with
  // X = 0 mod 16, so slot = (g + (cc>>1)) & 3 for every tile/fragment.
  const int sl8 = ((g + (cc >> 1)) & 3) * 8;

  f32x4 sacc[4][4] = {}, gacc[4][4] = {};
  float se_pk = 0.f, ac_pk = 0.f;   // lane-packed running sums

  // stage all 4 k-slices of unit n into slot n%3 (6 gll16 per thread)
  auto stage_unit = [&](int n){
    int nn = (n >= NU) ? n - NU : n;       // tail wrap: harmless re-loads
    us* sb = lds + (n % 3) * SLOT_SH;
    const int k32 = (nn & 31) * BK;
    const size_t stoff = (size_t)(nn >> 5) * STB * DD;
    gll16(Ub + k32 + offA, sb + tid*8);
    gll16(Fb + k32 + offA, sb + U_SH + tid*8);
    const us* pZ = Zb + stoff + k32 + offA;
    gll16(pZ,          sb + 2*U_SH + tid*8);
    gll16(pZ + 128*DD, sb + 2*U_SH + 4096 + tid*8);
    const us* pX = Xb + stoff + k32 + offA;
    gll16(pX,          sb + 2*U_SH + Z_SH + tid*8);
    gll16(pX + 128*DD, sb + 2*U_SH + Z_SH + 4096 + tid*8);
  };

  stage_unit(0);
  stage_unit(1);

#pragma unroll 1
  for (int u = 0; u < NU; ++u){
    // own unit-u loads landed; unit-(u+1)'s 6 stay in flight (never drain).
    asm volatile("s_waitcnt vmcnt(6)" ::: "memory");
    __builtin_amdgcn_s_barrier();
    // post-barrier issue: WAR-safe (slot (u+2)%3 readers all done above).
    stage_unit(u + 2);

    const us* sb = lds + (u % 3) * SLOT_SH;
    const us* tU = sb;
    const us* tF = sb + U_SH;
    const us* tZ = sb + 2*U_SH;
    const us* tX = sb + 2*U_SH + Z_SH;

    bf16x8 a0[4], b0[4], a1[4], b1[4];
#pragma unroll
    for (int f = 0; f < 4; ++f)
      a0[f] = *(const AS3 bf16x8*)(tU + (wl*64 + f*16 + cc)*BK + sl8);
#pragma unroll
    for (int f = 0; f < 4; ++f)
      b0[f] = *(const AS3 bf16x8*)(tZ + (ws*64 + f*16 + cc)*BK + sl8);
    __builtin_amdgcn_s_setprio(1);
#pragma unroll
    for (int fm = 0; fm < 4; ++fm)
#pragma unroll
      for (int fn = 0; fn < 4; ++fn)
        sacc[fm][fn] = __builtin_amdgcn_mfma_f32_16x16x32_bf16(a0[fm], b0[fn], sacc[fm][fn], 0, 0, 0);
    __builtin_amdgcn_s_setprio(0);

#pragma unroll
    for (int f = 0; f < 4; ++f)
      a1[f] = *(const AS3 bf16x8*)(tF + (wl*64 + f*16 + cc)*BK + sl8);
#pragma unroll
    for (int f = 0; f < 4; ++f)
      b1[f] = *(const AS3 bf16x8*)(tX + (ws*64 + f*16 + cc)*BK + sl8);
    __builtin_amdgcn_s_setprio(1);
#pragma unroll
    for (int fm = 0; fm < 4; ++fm)
#pragma unroll
      for (int fn = 0; fn < 4; ++fn)
        gacc[fm][fn] = __builtin_amdgcn_mfma_f32_16x16x32_bf16(a1[fm], b1[fn], gacc[fm][fn], 0, 0, 0);
    __builtin_amdgcn_s_setprio(0);

    // end of s-tile: exp-weight scores, fold G, butterfly-reduce over the
    // 16 s-columns (cc lanes), lane-pack into (se_pk, ac_pk), reset accs.
    if ((u & 31) == 31){
#pragma unroll
      for (int fm = 0; fm < 4; ++fm)
#pragma unroll
        for (int r = 0; r < 4; ++r){
          float ps = 0.f, pg = 0.f;
#pragma unroll
          for (int fn = 0; fn < 4; ++fn){
            float p = __expf(sacc[fm][fn][r]);   // |score| << 88, max-free safe
            ps += p;
            pg += p * gacc[fm][fn][r];
          }
#pragma unroll
          for (int m = 1; m < 16; m <<= 1){
            ps += __shfl_xor(ps, m, 64);
            pg += __shfl_xor(pg, m, 64);
          }
          bool sel = (cc == fm*4 + r);
          se_pk += sel ? ps : 0.f;
          ac_pk += sel ? pg : 0.f;
        }
#pragma unroll
      for (int fm = 0; fm < 4; ++fm)
#pragma unroll
        for (int fn = 0; fn < 4; ++fn){
          sacc[fm][fn] = f32x4{0.f, 0.f, 0.f, 0.f};
          gacc[fm][fn] = f32x4{0.f, 0.f, 0.f, 0.f};
        }
    }
  }

  // lane (g, cc) holds the (se, ac) sums for row (cc>>2)*16 + 4g + (cc&3)
  // of its wave's 64-row L-slice; each wave's ws is a separate partial.
  {
    int row = (cc >> 2)*16 + 4*g + (cc & 3);
    int l = lt*LT_ + wl*64 + row;
    size_t idx = ((size_t)b*LL + l)*4 + ws;
    pse[idx] = se_pk;
    pac[idx] = ac_pk;
  }
}

__global__ void combine_kernel(const float* __restrict__ pse, const float* __restrict__ pac,
                               const float* __restrict__ fb, float* __restrict__ out)
{
  int i = blockIdx.x*blockDim.x + threadIdx.x;
  if (i >= BB*LL) return;
  int l = i & (LL - 1);
  float s = 0.f, a = 0.f;
#pragma unroll
  for (int k = 0; k < 4; ++k){
    s += pse[(size_t)i*4 + k];
    a += pac[(size_t)i*4 + k];
  }
  out[i] = a / s + fb[l];
}

extern "C" void kernel_launch(void* const* d_in, const int* in_sizes, int n_in,
                              void* d_out, int out_size, void* d_ws, size_t ws_size,
                              hipStream_t stream)
{
  const float* inp = (const float*)d_in[0];   // [B,S,D]
  const float* Ww  = (const float*)d_in[1];   // [D,D]
  const float* Wb  = (const float*)d_in[2];   // [D]
  const float* Uw  = (const float*)d_in[3];   // [L,D]
  const float* Fw  = (const float*)d_in[4];   // [L,D]
  const float* fb  = (const float*)d_in[5];   // [L]
  float* out = (float*)d_out;

  char* ws = (char*)d_ws;
  us* Xbf = (us*)(ws);                            // 32 MiB
  us* Zbf = (us*)(ws + (size_t)32*1024*1024);     // 32 MiB
  us* Ubf = (us*)(ws + (size_t)64*1024*1024);     // 16 MiB
  us* Fbf = (us*)(ws + (size_t)80*1024*1024);     // 16 MiB
  us* Wbf = (us*)(ws + (size_t)96*1024*1024);     //  2 MiB
  float* pse = (float*)(ws + (size_t)98*1024*1024);   // 512 KiB
  float* pac = (float*)(ws + (size_t)99*1024*1024);   // 512 KiB

  conv_kernel<<<2048, 256, 0, stream>>>((const float4*)inp, (ushort4*)Xbf, BB*SS*DD/4);
  conv_kernel<<<256,  256, 0, stream>>>((const float4*)Ww,  (ushort4*)Wbf, DD*DD/4);
  conv_kernel<<<1024, 256, 0, stream>>>((const float4*)Uw,  (ushort4*)Ubf, LL*DD/4);
  conv_kernel<<<1024, 256, 0, stream>>>((const float4*)Fw,  (ushort4*)Fbf, LL*DD/4);

  zgemm_kernel<<<128*8, 256, 0, stream>>>(Xbf, Wbf, Wb, Zbf);
  fused_kernel<<<256, 512, 0, stream>>>(Ubf, Fbf, Zbf, Xbf, pse, pac);
  combine_kernel<<<(BB*LL + 255)/256, 256, 0, stream>>>(pse, pac, fb, out);
}

// Round 8
// 632.330 us; speedup vs baseline: 1.4621x; 1.0213x over previous
//
#include <hip/hip_runtime.h>

typedef __attribute__((ext_vector_type(8))) short bf16x8;
typedef __attribute__((ext_vector_type(4))) float f32x4;
typedef unsigned short us;

#define DEVINL __device__ __forceinline__
#define AS1 __attribute__((address_space(1)))
#define AS3 __attribute__((address_space(3)))

constexpr int BB = 4, SS = 4096, DD = 1024, LL = 8192;
// fused-kernel geometry
constexpr int LT_ = 128;            // L rows per block
constexpr int STB = 256;            // S rows per block-tile
constexpr int BK  = 32;             // K per unit
constexpr int NST = SS / STB;       // 16 s-tiles
constexpr int KST = DD / BK;        // 32 k-steps
constexpr int NU  = NST * KST;      // 512 units
constexpr int U_SH = LT_ * BK;      // 4096 shorts (8 KiB)
constexpr int Z_SH = STB * BK;      // 8192 shorts (16 KiB)
constexpr int SLOT_SH = 2*U_SH + 2*Z_SH;   // 24576 shorts (48 KiB)
// zgemm geometry
constexpr int ZKST = DD / 64;       // 16

DEVINL unsigned short f2bf(float f){
  union { float f; unsigned u; } a; a.f = f;
  unsigned r = a.u + 0x7fffu + ((a.u >> 16) & 1u);   // RNE
  return (unsigned short)(r >> 16);
}

DEVINL void gll16(const void* src, void* dst){
  __builtin_amdgcn_global_load_lds((const AS1 unsigned int*)src,
                                   (AS3 unsigned int*)dst, 16, 0, 0);
}

__global__ void conv_kernel(const float4* __restrict__ in,
                            ushort4* __restrict__ out, int n4){
  int stride = gridDim.x * blockDim.x;
  for (int i = blockIdx.x*blockDim.x + threadIdx.x; i < n4; i += stride){
    float4 v = in[i];
    ushort4 o;
    o.x = f2bf(v.x); o.y = f2bf(v.y); o.z = f2bf(v.z); o.w = f2bf(v.w);
    out[i] = o;
  }
}

// ---------------- zgemm (round-1 structure, proven, 0 conflicts) ---------
constexpr int ZTILE = 128 * 64;   // shorts per staged tile (BK=64 here)

DEVINL bf16x8 zread_frag(const us* tile, int row, int chunk){
  return *(const AS3 bf16x8*)(tile + row*64 + ((chunk ^ (row & 7)) << 3));
}

DEVINL void stage_tile128(const us* __restrict__ g0, int row0, int d0,
                          us* ldsbase, int wave, int lane){
#pragma unroll
  for (int it = 0; it < 4; ++it){
    int off  = it*4096 + wave*1024 + lane*16;   // byte offset inside tile
    int row  = off >> 7;                        // 128 B per row
    int slot = (off >> 4) & 7;
    int scol = (slot ^ (row & 7)) << 3;
    gll16(g0 + (size_t)(row0 + row) * DD + d0 + scol,
          ldsbase + ((it*4096 + wave*1024) >> 1));
  }
}

__global__ __launch_bounds__(256, 2) void zgemm_kernel(
    const us* __restrict__ X, const us* __restrict__ W,
    const float* __restrict__ Wb, us* __restrict__ Z)
{
  __shared__ __align__(16) us lds[2*ZTILE];   // 32 KiB
  const int bid = blockIdx.x;
  const int tm = bid & 127;
  const int tn = bid >> 7;
  const int tid = threadIdx.x, wave = tid >> 6, lane = tid & 63;
  const int wl = wave >> 1, wn = wave & 1;
  const int g = lane >> 4, cc = lane & 15;

  f32x4 acc[4][4] = {};
#pragma unroll 1
  for (int ks = 0; ks < ZKST; ++ks){
    __syncthreads();
    stage_tile128(X, tm*128, ks*64, lds,         wave, lane);
    stage_tile128(W, tn*128, ks*64, lds + ZTILE, wave, lane);
    __syncthreads();
#pragma unroll
    for (int ksub = 0; ksub < 2; ++ksub){
      bf16x8 af[4], bfr[4];
#pragma unroll
      for (int f = 0; f < 4; ++f) af[f]  = zread_frag(lds,         wl*64 + f*16 + cc, ksub*4 + g);
#pragma unroll
      for (int f = 0; f < 4; ++f) bfr[f] = zread_frag(lds + ZTILE, wn*64 + f*16 + cc, ksub*4 + g);
#pragma unroll
      for (int fm = 0; fm < 4; ++fm)
#pragma unroll
        for (int fn = 0; fn < 4; ++fn)
          acc[fm][fn] = __builtin_amdgcn_mfma_f32_16x16x32_bf16(af[fm], bfr[fn], acc[fm][fn], 0, 0, 0);
    }
  }
#pragma unroll
  for (int fm = 0; fm < 4; ++fm)
#pragma unroll
    for (int fn = 0; fn < 4; ++fn)
#pragma unroll
      for (int r = 0; r < 4; ++r){
        int row = tm*128 + wl*64 + fm*16 + 4*g + r;
        int col = tn*128 + wn*64 + fn*16 + cc;
        float y = acc[fm][fn][r] + Wb[col];
        float e2 = __expf(2.f * y);
        float t = 1.f - 2.f / (e2 + 1.f);
        Z[(size_t)row*DD + col] = f2bf(t);
      }
}

// ---------------- fused: deep-pipelined dual-GEMM + exp-weighted reduce ---
// Round-7 structure + depth-3 stage prefetch + cross-unit FRAGMENT
// prefetch. Invariants per unit u (one s_barrier per unit):
//   issued stages <= u+2 entering the body; vmcnt(6) before barrier waits
//   stage(u+1) (6 = stage(u+2) outstanding) -> after barrier(u) EVERY
//   wave's stage(u+1) has landed -> slot u+1 is readable during unit u's
//   tail (the pa/pb fragment prefetch for MFMA1 of u+1).
//   stage(u+3) (post-barrier) targets slot u%3: its last readers are the
//   a1/b1 reads of unit u, complete before each wave's barrier ✓.
__global__ __launch_bounds__(512, 2) void fused_kernel(
    const us* __restrict__ U, const us* __restrict__ F,
    const us* __restrict__ Z, const us* __restrict__ X,
    float* __restrict__ pse, float* __restrict__ pac)
{
  __shared__ __align__(16) us lds[3 * SLOT_SH];   // 144 KiB

  const int h = blockIdx.x;            // 256 blocks, 1 per CU
  const int xcd = h & 7, j = h >> 3;   // j in 0..31
  const int lt = xcd * 8 + (j & 7);    // 0..63
  const int b  = j >> 3;               // 0..3

  const int tid = threadIdx.x;
  const int wave = tid >> 6, lane = tid & 63;
  const int wl = wave >> 2, ws = wave & 3;     // 2 L-waves x 4 S-waves
  const int g = lane >> 4, cc = lane & 15;

  const us* Ub = U + (size_t)lt * LT_ * DD;
  const us* Fb = F + (size_t)lt * LT_ * DD;
  const us* Zb = Z + (size_t)b * SS * DD;
  const us* Xb = X + (size_t)b * SS * DD;

  // staging: LDS chunk c=tid -> row c>>2, slot c&3; fetch logical chunk
  // lg = ((c&3) - (c>>3)) & 3 (bank-conflict swizzle, round-7, verified 0).
  const int lg   = ((tid & 3) - (tid >> 3)) & 3;
  const int offA = (tid >> 2) * DD + lg * 8;

  // read-side swizzled slot (in shorts)
  const int sl8 = ((g + (cc >> 1)) & 3) * 8;

  // per-wave LDS row bases for fragment reads
  const int arow = (wl*64 + cc) * BK + sl8;   // + f*16*BK per fragment
  const int brow = (ws*64 + cc) * BK + sl8;

  f32x4 sacc[4][4] = {}, gacc[4][4] = {};
  float se_pk = 0.f, ac_pk = 0.f;   // lane-packed running sums

  auto stage_unit = [&](int n){
    int nn = (n >= NU) ? n - NU : n;       // tail wrap: harmless re-loads
    us* sb = lds + (n % 3) * SLOT_SH;
    const int k32 = (nn & 31) * BK;
    const size_t stoff = (size_t)(nn >> 5) * STB * DD;
    gll16(Ub + k32 + offA, sb + tid*8);
    gll16(Fb + k32 + offA, sb + U_SH + tid*8);
    const us* pZ = Zb + stoff + k32 + offA;
    gll16(pZ,          sb + 2*U_SH + tid*8);
    gll16(pZ + 128*DD, sb + 2*U_SH + 4096 + tid*8);
    const us* pX = Xb + stoff + k32 + offA;
    gll16(pX,          sb + 2*U_SH + Z_SH + tid*8);
    gll16(pX + 128*DD, sb + 2*U_SH + Z_SH + 4096 + tid*8);
  };

  stage_unit(0);
  stage_unit(1);
  stage_unit(2);
  asm volatile("s_waitcnt vmcnt(12)" ::: "memory");   // stage(0) landed
  __builtin_amdgcn_s_barrier();                       // ...for all waves

  // prime MFMA1 fragments for unit 0 (slot 0)
  bf16x8 pa[4], pb[4];
#pragma unroll
  for (int f = 0; f < 4; ++f)
    pa[f] = *(const AS3 bf16x8*)(lds + arow + f*16*BK);
#pragma unroll
  for (int f = 0; f < 4; ++f)
    pb[f] = *(const AS3 bf16x8*)(lds + 2*U_SH + brow + f*16*BK);

#pragma unroll 1
  for (int u = 0; u < NU; ++u){
    const us* sb = lds + (u % 3) * SLOT_SH;
    const us* tF = sb + U_SH;
    const us* tX = sb + 2*U_SH + Z_SH;

    // issue GEMM2 fragment reads early; latency hides under MFMA1
    bf16x8 a1[4], b1[4];
#pragma unroll
    for (int f = 0; f < 4; ++f)
      a1[f] = *(const AS3 bf16x8*)(tF + arow + f*16*BK);
#pragma unroll
    for (int f = 0; f < 4; ++f)
      b1[f] = *(const AS3 bf16x8*)(tX + brow + f*16*BK);
    __builtin_amdgcn_sched_barrier(0);

    __builtin_amdgcn_s_setprio(1);
#pragma unroll
    for (int fm = 0; fm < 4; ++fm)
#pragma unroll
      for (int fn = 0; fn < 4; ++fn)
        sacc[fm][fn] = __builtin_amdgcn_mfma_f32_16x16x32_bf16(pa[fm], pb[fn], sacc[fm][fn], 0, 0, 0);
    __builtin_amdgcn_s_setprio(0);

    __builtin_amdgcn_s_setprio(1);
#pragma unroll
    for (int fm = 0; fm < 4; ++fm)
#pragma unroll
      for (int fn = 0; fn < 4; ++fn)
        gacc[fm][fn] = __builtin_amdgcn_mfma_f32_16x16x32_bf16(a1[fm], b1[fn], gacc[fm][fn], 0, 0, 0);
    __builtin_amdgcn_s_setprio(0);

    // stage(u+1) landed for THIS wave; stage(u+2)'s 6 stay in flight.
    asm volatile("s_waitcnt vmcnt(6)" ::: "memory");
    __builtin_amdgcn_s_barrier();
    // post-barrier: every wave's stage(u+1) landed; slot u%3 fully read.
    stage_unit(u + 3);

    // fragment prefetch for unit u+1 (slot (u+1)%3, visible to all waves)
    {
      int un = u + 1; if (un >= NU) un -= NU;   // wrap: dead read, safe
      const us* sn = lds + (un % 3) * SLOT_SH;
#pragma unroll
      for (int f = 0; f < 4; ++f)
        pa[f] = *(const AS3 bf16x8*)(sn + arow + f*16*BK);
#pragma unroll
      for (int f = 0; f < 4; ++f)
        pb[f] = *(const AS3 bf16x8*)(sn + 2*U_SH + brow + f*16*BK);
    }
    __builtin_amdgcn_sched_barrier(0);

    // end of s-tile: exp-weight scores, fold G, butterfly-reduce over the
    // 16 s-columns (cc lanes), lane-pack into (se_pk, ac_pk), reset accs.
    if ((u & 31) == 31){
#pragma unroll
      for (int fm = 0; fm < 4; ++fm)
#pragma unroll
        for (int r = 0; r < 4; ++r){
          float ps = 0.f, pg = 0.f;
#pragma unroll
          for (int fn = 0; fn < 4; ++fn){
            float p = __expf(sacc[fm][fn][r]);   // |score| << 88, max-free safe
            ps += p;
            pg += p * gacc[fm][fn][r];
          }
#pragma unroll
          for (int m = 1; m < 16; m <<= 1){
            ps += __shfl_xor(ps, m, 64);
            pg += __shfl_xor(pg, m, 64);
          }
          bool sel = (cc == fm*4 + r);
          se_pk += sel ? ps : 0.f;
          ac_pk += sel ? pg : 0.f;
        }
#pragma unroll
      for (int fm = 0; fm < 4; ++fm)
#pragma unroll
        for (int fn = 0; fn < 4; ++fn){
          sacc[fm][fn] = f32x4{0.f, 0.f, 0.f, 0.f};
          gacc[fm][fn] = f32x4{0.f, 0.f, 0.f, 0.f};
        }
    }
  }

  // lane (g, cc) holds the (se, ac) sums for row (cc>>2)*16 + 4g + (cc&3)
  {
    int row = (cc >> 2)*16 + 4*g + (cc & 3);
    int l = lt*LT_ + wl*64 + row;
    size_t idx = ((size_t)b*LL + l)*4 + ws;
    pse[idx] = se_pk;
    pac[idx] = ac_pk;
  }
}

__global__ void combine_kernel(const float* __restrict__ pse, const float* __restrict__ pac,
                               const float* __restrict__ fb, float* __restrict__ out)
{
  int i = blockIdx.x*blockDim.x + threadIdx.x;
  if (i >= BB*LL) return;
  int l = i & (LL - 1);
  float s = 0.f, a = 0.f;
#pragma unroll
  for (int k = 0; k < 4; ++k){
    s += pse[(size_t)i*4 + k];
    a += pac[(size_t)i*4 + k];
  }
  out[i] = a / s + fb[l];
}

extern "C" void kernel_launch(void* const* d_in, const int* in_sizes, int n_in,
                              void* d_out, int out_size, void* d_ws, size_t ws_size,
                              hipStream_t stream)
{
  const float* inp = (const float*)d_in[0];   // [B,S,D]
  const float* Ww  = (const float*)d_in[1];   // [D,D]
  const float* Wb  = (const float*)d_in[2];   // [D]
  const float* Uw  = (const float*)d_in[3];   // [L,D]
  const float* Fw  = (const float*)d_in[4];   // [L,D]
  const float* fb  = (const float*)d_in[5];   // [L]
  float* out = (float*)d_out;

  char* ws = (char*)d_ws;
  us* Xbf = (us*)(ws);                            // 32 MiB
  us* Zbf = (us*)(ws + (size_t)32*1024*1024);     // 32 MiB
  us* Ubf = (us*)(ws + (size_t)64*1024*1024);     // 16 MiB
  us* Fbf = (us*)(ws + (size_t)80*1024*1024);     // 16 MiB
  us* Wbf = (us*)(ws + (size_t)96*1024*1024);     //  2 MiB
  float* pse = (float*)(ws + (size_t)98*1024*1024);   // 512 KiB
  float* pac = (float*)(ws + (size_t)99*1024*1024);   // 512 KiB

  conv_kernel<<<2048, 256, 0, stream>>>((const float4*)inp, (ushort4*)Xbf, BB*SS*DD/4);
  conv_kernel<<<256,  256, 0, stream>>>((const float4*)Ww,  (ushort4*)Wbf, DD*DD/4);
  conv_kernel<<<1024, 256, 0, stream>>>((const float4*)Uw,  (ushort4*)Ubf, LL*DD/4);
  conv_kernel<<<1024, 256, 0, stream>>>((const float4*)Fw,  (ushort4*)Fbf, LL*DD/4);

  zgemm_kernel<<<128*8, 256, 0, stream>>>(Xbf, Wbf, Wb, Zbf);
  fused_kernel<<<256, 512, 0, stream>>>(Ubf, Fbf, Zbf, Xbf, pse, pac);
  combine_kernel<<<(BB*LL + 255)/256, 256, 0, stream>>>(pse, pac, fb, out);
}